// Round 13
// baseline (132.146 us; speedup 1.0000x reference)
//
#include <hip/hip_runtime.h>

#define HIDDEN 768
#define HEADS 12
#define HEAD_DIM 64
#define DEPTH 8
#define BB 4
#define SS 512
#define MM (BB * SS)           // 2048
#define NQD (HIDDEN * DEPTH)   // 6144

typedef __bf16 bf16x8 __attribute__((ext_vector_type(8)));
typedef float f32x4 __attribute__((ext_vector_type(4)));
typedef float f32x16 __attribute__((ext_vector_type(16)));
typedef unsigned short u16x8 __attribute__((ext_vector_type(8)));

static __device__ __forceinline__ unsigned short f2bf(float f) {
  union { float f; unsigned u; } c; c.f = f;
  unsigned u = c.u;
  u = u + 0x7fffu + ((u >> 16) & 1u);   // RNE
  return (unsigned short)(u >> 16);
}

static __device__ __forceinline__ unsigned cvt_pk_bf16(float lo, float hi) {
  unsigned r;
  asm("v_cvt_pk_bf16_f32 %0, %1, %2" : "=v"(r) : "v"(lo), "v"(hi));
  return r;
}

static __device__ __forceinline__ void gld16(const void* g, void* l) {
  __builtin_amdgcn_global_load_lds((const __attribute__((address_space(1))) void*)g,
                                   (__attribute__((address_space(3))) void*)l, 16, 0, 0);
}

// ---------------------------------------------------------------- converts (hs + Wv only)
__global__ void convert2_f32_bf16(const float* __restrict__ s0, unsigned short* __restrict__ d0,
                                  int n4_0, const float* __restrict__ s1,
                                  unsigned short* __restrict__ d1, int n4_1) {
  int i = blockIdx.x * blockDim.x + threadIdx.x;
  const float* src; unsigned short* dst; int j;
  if (i < n4_0) { src = s0; dst = d0; j = i; }
  else { j = i - n4_0; if (j >= n4_1) return; src = s1; dst = d1; }
  float4 v = reinterpret_cast<const float4*>(src)[j];
  ushort4 o;
  o.x = f2bf(v.x); o.y = f2bf(v.y); o.z = f2bf(v.z); o.w = f2bf(v.w);
  reinterpret_cast<ushort4*>(dst)[j] = o;
}

// ---------------------------------------------------------------- small GEMM (Vt): unchanged 128x128 structure
__global__ __launch_bounds__(256) void gemm_bt(
    const unsigned short* __restrict__ A, const unsigned short* __restrict__ W,
    const float* __restrict__ bias, unsigned short* __restrict__ out0, int K) {
  __shared__ unsigned short At[2][4096];
  __shared__ unsigned short Bt[2][4096];
  const int tid = threadIdx.x;
  const int nwg = gridDim.x * gridDim.y;
  const int orig = blockIdx.y * gridDim.x + blockIdx.x;
  const int wg = (orig & 7) * (nwg >> 3) + (orig >> 3);
  const int bm = (wg % gridDim.x) * 128;
  const int bn = (wg / gridDim.x) * 128;
  const int wave = tid >> 6, lane = tid & 63;
  const int wm = (wave >> 1) * 64, wn = (wave & 1) * 64;
  const int lg = lane >> 4, lr = lane & 15;
  const int srow = tid >> 2, scol = (tid & 3) * 8;
  f32x4 acc[4][4] = {};
  const unsigned short* aptr = A + (size_t)(bm + srow) * K + scol;
  const unsigned short* wptr = W + (size_t)(bn + srow) * K + scol;

  auto stage = [&](int buf, int k0) {
    gld16(aptr + k0,                  &At[buf][tid * 8]);
    gld16(aptr + (size_t)64 * K + k0, &At[buf][2048 + tid * 8]);
    gld16(wptr + k0,                  &Bt[buf][tid * 8]);
    gld16(wptr + (size_t)64 * K + k0, &Bt[buf][2048 + tid * 8]);
  };

  stage(0, 0);
  __syncthreads();

  int cur = 0;
  for (int k0 = 32; k0 <= K; k0 += 32) {
    if (k0 < K) stage(cur ^ 1, k0);
    bf16x8 af[4], bfr[4];
#pragma unroll
    for (int mi = 0; mi < 4; ++mi)
      af[mi] = *reinterpret_cast<const bf16x8*>(&At[cur][(wm + mi * 16 + lr) * 32 + lg * 8]);
#pragma unroll
    for (int ni = 0; ni < 4; ++ni)
      bfr[ni] = *reinterpret_cast<const bf16x8*>(&Bt[cur][(wn + ni * 16 + lr) * 32 + lg * 8]);
#pragma unroll
    for (int mi = 0; mi < 4; ++mi)
#pragma unroll
      for (int ni = 0; ni < 4; ++ni)
        acc[mi][ni] = __builtin_amdgcn_mfma_f32_16x16x32_bf16(af[mi], bfr[ni], acc[mi][ni], 0, 0, 0);
    __syncthreads();
    cur ^= 1;
  }

#pragma unroll
  for (int mi = 0; mi < 4; ++mi)
#pragma unroll
    for (int ni = 0; ni < 4; ++ni)
#pragma unroll
      for (int i = 0; i < 4; ++i) {
        int m = bm + wm + mi * 16 + lg * 4 + i;   // Wv row (n_v)
        int n = bn + wn + ni * 16 + lr;           // X row (b*512+s)
        float v = acc[mi][ni][i] + bias[m];
        size_t addr = ((size_t)((n >> 9) * 12 + (m >> 6)) * 64 + (size_t)(m & 63)) * 512 + (size_t)(n & 511);
        out0[addr] = f2bf(v);
      }
}

// ---------------------------------------------------------------- big GEMM (Qd|Kd): 256x192 tile, 512 blocks (2/CU),
// 8 waves, BK=32, depth-2 reg-staged dbuf. W staged DIRECTLY from f32 Wqd/Wkd with
// inverse row-perm (fold of convert_w_perm2); bias via inverse-perm lookup.
// LDS content swizzled: byte ^= ((row>>1)&3)<<4 (on ds_write; read side fixed per lane).
__global__ __launch_bounds__(512, 2) void gemm_qk256(
    const unsigned short* __restrict__ A, const float* __restrict__ Wq,
    const float* __restrict__ Wk, const float* __restrict__ bq,
    const float* __restrict__ bk, unsigned short* __restrict__ out0,
    unsigned short* __restrict__ out1, int K) {
  __shared__ unsigned short At[2][8192];   // 256 x 32 (swizzled content)
  __shared__ unsigned short Bt[2][6144];   // 192 x 32 (swizzled content)
  const int tid = threadIdx.x;
  const int nwg = gridDim.x * gridDim.y;   // 512
  const int orig = blockIdx.y * gridDim.x + blockIdx.x;
  const int wg = (orig & 7) * (nwg >> 3) + (orig >> 3);
  const int bm = (wg % gridDim.x) * 256;
  const int bn = (wg / gridDim.x) * 192;   // never straddles NQD (NQD/192 == 32)
  const int wave = tid >> 6, lane = tid & 63;
  const int wr = wave >> 2, wc = wave & 3;          // 2(M) x 4(N)
  const int lg = lane >> 4, lr = lane & 15;
  const bool isK = (bn >= NQD);
  const float* Wsrc = isK ? Wk : Wq;
  const int bnh = isK ? bn - NQD : bn;              // permuted row base within half

  // staging granule map: thread -> (row, col-elem); swizzled LDS byte offsets
  const int rA0 = tid >> 2,           cA0 = (tid & 3) << 3;
  const int rA1 = (tid + 512) >> 2;                          // rows 128..255
  const bool hasB1 = tid < 256;
  const int rB1 = (tid + 512) >> 2;                          // rows 128..191 (tid<256)
  const int dA0 = rA0 * 64 + ((cA0 << 1) ^ (((rA0 >> 1) & 3) << 4));
  const int dA1 = rA1 * 64 + ((cA0 << 1) ^ (((rA1 >> 1) & 3) << 4));
  const int dB0 = dA0;
  const int dB1 = rB1 * 64 + ((cA0 << 1) ^ (((rB1 >> 1) & 3) << 4));
  const unsigned short* pA0 = A + (size_t)(bm + rA0) * K + cA0;
  const unsigned short* pA1 = A + (size_t)(bm + rA1) * K + cA0;
  // W: inverse-permuted source rows (perm: nr = h*512 + d*64 + e; orig = h*512 + e*8 + d)
  auto invrow = [](int r) { return (r & ~511) | ((r & 63) << 3) | ((r >> 6) & 7); };
  const float* pB0 = Wsrc + (size_t)invrow(bnh + rA0) * K + cA0;
  const float* pB1 = Wsrc + (size_t)invrow(bnh + rB1) * K + cA0;

  // two NAMED register staging sets (rule #20)
  u16x8 a0A = {}, a1A = {};
  u16x8 a0B = {}, a1B = {};
  float4 b0loA = {}, b0hiA = {}, b1loA = {}, b1hiA = {};
  float4 b0loB = {}, b0hiB = {}, b1loB = {}, b1hiB = {};

  auto cvt8 = [&](float4 lo, float4 hi) -> u16x8 {
    union { unsigned u[4]; u16x8 v; } r;
    r.u[0] = cvt_pk_bf16(lo.x, lo.y);
    r.u[1] = cvt_pk_bf16(lo.z, lo.w);
    r.u[2] = cvt_pk_bf16(hi.x, hi.y);
    r.u[3] = cvt_pk_bf16(hi.z, hi.w);
    return r.v;
  };

  auto gloadA = [&](int k0) {
    a0A = *reinterpret_cast<const u16x8*>(pA0 + k0);
    a1A = *reinterpret_cast<const u16x8*>(pA1 + k0);
    b0loA = *reinterpret_cast<const float4*>(pB0 + k0);
    b0hiA = *reinterpret_cast<const float4*>(pB0 + k0 + 4);
    if (hasB1) {
      b1loA = *reinterpret_cast<const float4*>(pB1 + k0);
      b1hiA = *reinterpret_cast<const float4*>(pB1 + k0 + 4);
    }
  };
  auto gloadB = [&](int k0) {
    a0B = *reinterpret_cast<const u16x8*>(pA0 + k0);
    a1B = *reinterpret_cast<const u16x8*>(pA1 + k0);
    b0loB = *reinterpret_cast<const float4*>(pB0 + k0);
    b0hiB = *reinterpret_cast<const float4*>(pB0 + k0 + 4);
    if (hasB1) {
      b1loB = *reinterpret_cast<const float4*>(pB1 + k0);
      b1hiB = *reinterpret_cast<const float4*>(pB1 + k0 + 4);
    }
  };
  auto lwriteA = [&](int buf) {
    *reinterpret_cast<u16x8*>((char*)At[buf] + dA0) = a0A;
    *reinterpret_cast<u16x8*>((char*)At[buf] + dA1) = a1A;
    *reinterpret_cast<u16x8*>((char*)Bt[buf] + dB0) = cvt8(b0loA, b0hiA);
    if (hasB1) *reinterpret_cast<u16x8*>((char*)Bt[buf] + dB1) = cvt8(b1loA, b1hiA);
  };
  auto lwriteB = [&](int buf) {
    *reinterpret_cast<u16x8*>((char*)At[buf] + dA0) = a0B;
    *reinterpret_cast<u16x8*>((char*)At[buf] + dA1) = a1B;
    *reinterpret_cast<u16x8*>((char*)Bt[buf] + dB0) = cvt8(b0loB, b0hiB);
    if (hasB1) *reinterpret_cast<u16x8*>((char*)Bt[buf] + dB1) = cvt8(b1loB, b1hiB);
  };

  // read-side swizzle depends only on lr (row bases are multiples of 16)
  const int rdswz = ((((lr >> 1) & 3) ^ lg) << 4);   // byte offset within 64B row

  f32x4 acc[8][3] = {};
  auto compute = [&](int buf) {
    bf16x8 af[8], bfr[3];
    const char* abase = (const char*)At[buf];
    const char* bbase = (const char*)Bt[buf];
#pragma unroll
    for (int mi = 0; mi < 8; ++mi) {
      const int row = wr * 128 + mi * 16 + lr;
      af[mi] = *reinterpret_cast<const bf16x8*>(abase + row * 64 + rdswz);
    }
#pragma unroll
    for (int ni = 0; ni < 3; ++ni) {
      const int row = wc * 48 + ni * 16 + lr;
      bfr[ni] = *reinterpret_cast<const bf16x8*>(bbase + row * 64 + rdswz);
    }
#pragma unroll
    for (int mi = 0; mi < 8; ++mi)
#pragma unroll
      for (int ni = 0; ni < 3; ++ni)
        acc[mi][ni] = __builtin_amdgcn_mfma_f32_16x16x32_bf16(af[mi], bfr[ni], acc[mi][ni], 0, 0, 0);
  };

  const int NT = K / 32;                 // 24 (even)
  gloadA(0);
  gloadB(32);
  lwriteA(0);
  __syncthreads();

  for (int tt = 0; tt < NT; tt += 2) {
    if (tt + 2 < NT) gloadA((tt + 2) * 32);
    compute(0);
    if (tt + 1 < NT) lwriteB(1);
    __syncthreads();
    if (tt + 1 < NT) {
      if (tt + 3 < NT) gloadB((tt + 3) * 32);
      compute(1);
      if (tt + 2 < NT) lwriteA(0);
      __syncthreads();
    }
  }

  unsigned short* outp = isK ? out1 : out0;
  const float* biasp = isK ? bk : bq;
  const float scale = isK ? 1.0f : 0.125f;   // Qd pre-scaled by 1/8
#pragma unroll
  for (int mi = 0; mi < 8; ++mi)
#pragma unroll
    for (int ni = 0; ni < 3; ++ni)
#pragma unroll
      for (int i = 0; i < 4; ++i) {
        int m = bm + wr * 128 + mi * 16 + lg * 4 + i;
        int nr = bnh + wc * 48 + ni * 16 + lr;          // permuted col within half
        float v = (acc[mi][ni][i] + biasp[invrow(nr)]) * scale;
        size_t addr = ((size_t)(((m >> 9) * 12 + (nr >> 9)) * 8 + ((nr >> 6) & 7)) * 512 + (size_t)(m & 511)) * 64 + (size_t)(nr & 63);
        outp[addr] = f2bf(v);
      }
}

// ---------------------------------------------------------------- fused attention, 32x32 swapped structure (+ T5 setprio)
__global__ __launch_bounds__(256) void attn32(
    const unsigned short* __restrict__ Qd, const unsigned short* __restrict__ Kd,
    const unsigned short* __restrict__ Vt, const int* __restrict__ mask,
    float* __restrict__ out) {
  __shared__ unsigned char KsB[64 * 128];   // [k][e] bf16, byte^((row&7)<<4) swizzle
  __shared__ unsigned char VsB[64 * 128];   // [e][k] bf16, same swizzle
  __shared__ float mLds[64];
  __shared__ int mflag;
  const int tid = threadIdx.x;
  const int bid = blockIdx.x;
  const int qt = bid & 3;
  const int inst = bid >> 2;         // (b*12+h)*8 + d
  const int bh = inst >> 3;
  const int b = bh / 12;
  const int wave = tid >> 6, lane = tid & 63;
  const int l31 = lane & 31, hi = lane >> 5;
  const size_t qkbase = (size_t)inst * (SS * 64);
  const size_t vbase = (size_t)bh * (64 * SS);

  if (tid == 0) mflag = 0;
  __syncthreads();
  {
    int m0 = mask[b * SS + tid], m1 = mask[b * SS + 256 + tid];
    if ((m0 == 0) || (m1 == 0)) mflag = 1;
  }
  __syncthreads();
  const bool hasmask = (mflag != 0);

  const int q0w = qt * 128 + wave * 32;
  bf16x8 aq[4];
  {
    const unsigned short* qrow = Qd + qkbase + (size_t)(q0w + l31) * 64 + 8 * hi;
#pragma unroll
    for (int s = 0; s < 4; ++s)
      aq[s] = *reinterpret_cast<const bf16x8*>(qrow + 16 * s);
  }

  const int sr = tid >> 3;
  const int sc = (tid & 7) * 8;
  const int swz_lo = sr * 128 + ((sc * 2) ^ ((sr & 7) << 4));
  const int swz_hi = (sr + 32) * 128 + ((sc * 2) ^ (((sr + 32) & 7) << 4));

  f32x16 o[2] = {};
  float psum = 0.f;

  u16x8 rk0 = *reinterpret_cast<const u16x8*>(&Kd[qkbase + (size_t)sr * 64 + sc]);
  u16x8 rk1 = *reinterpret_cast<const u16x8*>(&Kd[qkbase + (size_t)(sr + 32) * 64 + sc]);
  u16x8 rv0 = *reinterpret_cast<const u16x8*>(&Vt[vbase + (size_t)sr * SS + sc]);
  u16x8 rv1 = *reinterpret_cast<const u16x8*>(&Vt[vbase + (size_t)(sr + 32) * SS + sc]);

  for (int t = 0; t < SS / 64; ++t) {
    *reinterpret_cast<u16x8*>(KsB + swz_lo) = rk0;
    *reinterpret_cast<u16x8*>(KsB + swz_hi) = rk1;
    *reinterpret_cast<u16x8*>(VsB + swz_lo) = rv0;
    *reinterpret_cast<u16x8*>(VsB + swz_hi) = rv1;
    if (hasmask && tid < 64) mLds[tid] = mask[b * SS + t * 64 + tid] ? 0.f : -1e9f;
    __syncthreads();

    if (t < SS / 64 - 1) {
      const int kn = (t + 1) * 64;
      rk0 = *reinterpret_cast<const u16x8*>(&Kd[qkbase + (size_t)(kn + sr) * 64 + sc]);
      rk1 = *reinterpret_cast<const u16x8*>(&Kd[qkbase + (size_t)(kn + sr + 32) * 64 + sc]);
      rv0 = *reinterpret_cast<const u16x8*>(&Vt[vbase + (size_t)sr * SS + kn + sc]);
      rv1 = *reinterpret_cast<const u16x8*>(&Vt[vbase + (size_t)(sr + 32) * SS + kn + sc]);
    }

    f32x16 st[2];
    __builtin_amdgcn_s_setprio(1);
#pragma unroll
    for (int kh = 0; kh < 2; ++kh) {
      f32x16 acc = {};
      const int row = kh * 32 + l31;
      const int rswz = (row & 7) << 4;
#pragma unroll
      for (int s = 0; s < 4; ++s) {
        bf16x8 ak = *reinterpret_cast<const bf16x8*>(KsB + row * 128 + ((32 * s + 16 * hi) ^ rswz));
        acc = __builtin_amdgcn_mfma_f32_32x32x16_bf16(ak, aq[s], acc, 0, 0, 0);
      }
      st[kh] = acc;
    }
    __builtin_amdgcn_s_setprio(0);

    if (hasmask) {
#pragma unroll
      for (int h = 0; h < 2; ++h)
#pragma unroll
        for (int r = 0; r < 16; ++r)
          st[h][r] += mLds[32 * h + (r & 3) + 8 * (r >> 2) + 4 * hi];
    }

    float pv[2][16];
#pragma unroll
    for (int h = 0; h < 2; ++h)
#pragma unroll
      for (int r = 0; r < 16; ++r) {
        float p = __expf(st[h][r]);
        psum += p;
        pv[h][r] = p;
      }

    __builtin_amdgcn_s_setprio(1);
#pragma unroll
    for (int ks = 0; ks < 4; ++ks) {
      const int h = ks >> 1, rb = 8 * (ks & 1);
      unsigned w0 = cvt_pk_bf16(pv[h][rb + 0], pv[h][rb + 1]);
      unsigned w1 = cvt_pk_bf16(pv[h][rb + 2], pv[h][rb + 3]);
      unsigned w2 = cvt_pk_bf16(pv[h][rb + 4], pv[h][rb + 5]);
      unsigned w3 = cvt_pk_bf16(pv[h][rb + 6], pv[h][rb + 7]);
      asm("v_permlane32_swap_b32 %0, %1" : "+v"(w0), "+v"(w2));
      asm("v_permlane32_swap_b32 %0, %1" : "+v"(w1), "+v"(w3));
      union { unsigned u[4]; bf16x8 v; } pa;
      pa.u[0] = w0; pa.u[1] = w1; pa.u[2] = w2; pa.u[3] = w3;
#pragma unroll
      for (int et = 0; et < 2; ++et) {
        const int vrow = 32 * et + l31;
        bf16x8 bv = *reinterpret_cast<const bf16x8*>(
            VsB + vrow * 128 + ((32 * ks + 16 * hi) ^ ((vrow & 7) << 4)));
        o[et] = __builtin_amdgcn_mfma_f32_32x32x16_bf16(pa.v, bv, o[et], 0, 0, 0);
      }
    }
    __builtin_amdgcn_s_setprio(0);
    __syncthreads();
  }

  psum += __shfl_xor(psum, 32);
  float inv = 1.f / psum;
  float iv[16];
#pragma unroll
  for (int r = 0; r < 16; ++r)
    iv[r] = __shfl(inv, (r & 3) + 8 * (r >> 2) + 4 * hi);

  const int d = inst & 7;
  const int hh = bh % 12;
  const size_t obase = (((size_t)d * BB + b) * HEADS + hh) * (SS * 64);
#pragma unroll
  for (int et = 0; et < 2; ++et)
#pragma unroll
    for (int r = 0; r < 16; ++r) {
      const int qrow = (r & 3) + 8 * (r >> 2) + 4 * hi;
      out[obase + (size_t)(q0w + qrow) * 64 + 32 * et + l31] = o[et][r] * iv[r];
    }
}

// ----------------------------------------------------------------
extern "C" void kernel_launch(void* const* d_in, const int* in_sizes, int n_in,
                              void* d_out, int out_size, void* d_ws, size_t ws_size,
                              hipStream_t stream) {
  const float* hs  = (const float*)d_in[0];
  const int* mask  = (const int*)d_in[1];
  const float* Wv  = (const float*)d_in[6];
  const float* bv  = (const float*)d_in[7];
  const float* Wqd = (const float*)d_in[8];
  const float* bqd = (const float*)d_in[9];
  const float* Wkd = (const float*)d_in[10];
  const float* bkd = (const float*)d_in[11];

  char* ws = (char*)d_ws;
  unsigned short* A_bf   = (unsigned short*)ws; ws += (size_t)MM * HIDDEN * 2;
  unsigned short* Wv_bf  = (unsigned short*)ws; ws += (size_t)HIDDEN * HIDDEN * 2;
  unsigned short* Qd     = (unsigned short*)ws; ws += (size_t)MM * NQD * 2;
  unsigned short* Kd     = (unsigned short*)ws; ws += (size_t)MM * NQD * 2;
  unsigned short* Vt     = (unsigned short*)ws; ws += (size_t)MM * HIDDEN * 2;

  {
    int a4 = MM * HIDDEN / 4, b4 = HIDDEN * HIDDEN / 4;
    convert2_f32_bf16<<<(a4 + b4 + 255) / 256, 256, 0, stream>>>(hs, A_bf, a4, Wv, Wv_bf, b4);
  }

  // V^T gemm: A=Wv (M=768), W=X (N=2048) -> Vt[bh][e][s]
  gemm_bt<<<dim3(HIDDEN / 128, MM / 128), 256, 0, stream>>>(
      Wv_bf, A_bf, bv, Vt, HIDDEN);
  // merged Qd|Kd gemm: A=X, W folded from f32 Wqd|Wkd (inverse-perm rows)
  gemm_qk256<<<dim3(MM / 256, 2 * NQD / 192), 512, 0, stream>>>(
      A_bf, Wqd, Wkd, bqd, bkd, Qd, Kd, HIDDEN);

  attn32<<<BB * HEADS * DEPTH * (SS / 128), 256, 0, stream>>>(Qd, Kd, Vt, mask, (float*)d_out);
}

// Round 14
// 132.123 us; speedup vs baseline: 1.0002x; 1.0002x over previous
//
#include <hip/hip_runtime.h>

#define HIDDEN 768
#define HEADS 12
#define HEAD_DIM 64
#define DEPTH 8
#define BB 4
#define SS 512
#define MM (BB * SS)           // 2048
#define NQD (HIDDEN * DEPTH)   // 6144

typedef __bf16 bf16x8 __attribute__((ext_vector_type(8)));
typedef float f32x4 __attribute__((ext_vector_type(4)));
typedef float f32x16 __attribute__((ext_vector_type(16)));
typedef unsigned short u16x8 __attribute__((ext_vector_type(8)));

static __device__ __forceinline__ unsigned short f2bf(float f) {
  union { float f; unsigned u; } c; c.f = f;
  unsigned u = c.u;
  u = u + 0x7fffu + ((u >> 16) & 1u);   // RNE
  return (unsigned short)(u >> 16);
}

static __device__ __forceinline__ unsigned cvt_pk_bf16(float lo, float hi) {
  unsigned r;
  asm("v_cvt_pk_bf16_f32 %0, %1, %2" : "=v"(r) : "v"(lo), "v"(hi));
  return r;
}

static __device__ __forceinline__ void gld16(const void* g, void* l) {
  __builtin_amdgcn_global_load_lds((const __attribute__((address_space(1))) void*)g,
                                   (__attribute__((address_space(3))) void*)l, 16, 0, 0);
}

// ---------------------------------------------------------------- converts
__global__ void convert2_f32_bf16(const float* __restrict__ s0, unsigned short* __restrict__ d0,
                                  int n4_0, const float* __restrict__ s1,
                                  unsigned short* __restrict__ d1, int n4_1) {
  int i = blockIdx.x * blockDim.x + threadIdx.x;
  const float* src; unsigned short* dst; int j;
  if (i < n4_0) { src = s0; dst = d0; j = i; }
  else { j = i - n4_0; if (j >= n4_1) return; src = s1; dst = d1; }
  float4 v = reinterpret_cast<const float4*>(src)[j];
  ushort4 o;
  o.x = f2bf(v.x); o.y = f2bf(v.y); o.z = f2bf(v.z); o.w = f2bf(v.w);
  reinterpret_cast<ushort4*>(dst)[j] = o;
}

// permute W rows [h][e][d] -> [h][d][e] while converting (row n_old = h*512+e*8+d)
__global__ void convert_w_perm2(const float* __restrict__ s0, const float* __restrict__ s1,
                                unsigned short* __restrict__ dst, int n4each) {
  int i = blockIdx.x * blockDim.x + threadIdx.x;
  const float* src = s0; unsigned short* d = dst; int j = i;
  if (i >= n4each) {
    j = i - n4each;
    if (j >= n4each) return;
    src = s1; d = dst + (size_t)NQD * HIDDEN;
  }
  int row = j / 192;                 // K/4 = 192 float4 per row
  int cg  = j - row * 192;
  int nr = (row & ~511) | ((row & 7) << 6) | ((row >> 3) & 63);
  float4 v = reinterpret_cast<const float4*>(src)[j];
  ushort4 o;
  o.x = f2bf(v.x); o.y = f2bf(v.y); o.z = f2bf(v.z); o.w = f2bf(v.w);
  reinterpret_cast<ushort4*>(&d[(size_t)nr * HIDDEN])[cg] = o;
}

__global__ void convert_bias_perm2(const float* __restrict__ s0, const float* __restrict__ s1,
                                   float* __restrict__ dst, int n) {
  int i = blockIdx.x * blockDim.x + threadIdx.x;
  const float* src = s0; float* d = dst; int j = i;
  if (i >= n) {
    j = i - n;
    if (j >= n) return;
    src = s1; d = dst + n;
  }
  int nr = (j & ~511) | ((j & 7) << 6) | ((j >> 3) & 63);
  d[nr] = src[j];
}

// ---------------------------------------------------------------- small GEMM (Vt): unchanged 128x128 structure
__global__ __launch_bounds__(256) void gemm_bt(
    const unsigned short* __restrict__ A, const unsigned short* __restrict__ W,
    const float* __restrict__ bias, unsigned short* __restrict__ out0, int K) {
  __shared__ unsigned short At[2][4096];
  __shared__ unsigned short Bt[2][4096];
  const int tid = threadIdx.x;
  const int nwg = gridDim.x * gridDim.y;
  const int orig = blockIdx.y * gridDim.x + blockIdx.x;
  const int wg = (orig & 7) * (nwg >> 3) + (orig >> 3);
  const int bm = (wg % gridDim.x) * 128;
  const int bn = (wg / gridDim.x) * 128;
  const int wave = tid >> 6, lane = tid & 63;
  const int wm = (wave >> 1) * 64, wn = (wave & 1) * 64;
  const int lg = lane >> 4, lr = lane & 15;
  const int srow = tid >> 2, scol = (tid & 3) * 8;
  f32x4 acc[4][4] = {};
  const unsigned short* aptr = A + (size_t)(bm + srow) * K + scol;
  const unsigned short* wptr = W + (size_t)(bn + srow) * K + scol;

  auto stage = [&](int buf, int k0) {
    gld16(aptr + k0,                  &At[buf][tid * 8]);
    gld16(aptr + (size_t)64 * K + k0, &At[buf][2048 + tid * 8]);
    gld16(wptr + k0,                  &Bt[buf][tid * 8]);
    gld16(wptr + (size_t)64 * K + k0, &Bt[buf][2048 + tid * 8]);
  };

  stage(0, 0);
  __syncthreads();

  int cur = 0;
  for (int k0 = 32; k0 <= K; k0 += 32) {
    if (k0 < K) stage(cur ^ 1, k0);
    bf16x8 af[4], bfr[4];
#pragma unroll
    for (int mi = 0; mi < 4; ++mi)
      af[mi] = *reinterpret_cast<const bf16x8*>(&At[cur][(wm + mi * 16 + lr) * 32 + lg * 8]);
#pragma unroll
    for (int ni = 0; ni < 4; ++ni)
      bfr[ni] = *reinterpret_cast<const bf16x8*>(&Bt[cur][(wn + ni * 16 + lr) * 32 + lg * 8]);
#pragma unroll
    for (int mi = 0; mi < 4; ++mi)
#pragma unroll
      for (int ni = 0; ni < 4; ++ni)
        acc[mi][ni] = __builtin_amdgcn_mfma_f32_16x16x32_bf16(af[mi], bfr[ni], acc[mi][ni], 0, 0, 0);
    __syncthreads();
    cur ^= 1;
  }

#pragma unroll
  for (int mi = 0; mi < 4; ++mi)
#pragma unroll
    for (int ni = 0; ni < 4; ++ni)
#pragma unroll
      for (int i = 0; i < 4; ++i) {
        int m = bm + wm + mi * 16 + lg * 4 + i;   // Wv row (n_v)
        int n = bn + wn + ni * 16 + lr;           // X row (b*512+s)
        float v = acc[mi][ni][i] + bias[m];
        size_t addr = ((size_t)((n >> 9) * 12 + (m >> 6)) * 64 + (size_t)(m & 63)) * 512 + (size_t)(n & 511);
        out0[addr] = f2bf(v);
      }
}

// ---------------------------------------------------------------- big GEMM (Qd|Kd): 256x192 tile, 512 blocks (2/CU),
// 8 waves, BK=32, DEPTH-2 reg-staged pipeline (named sets A/B), one barrier/phase.
// W is pre-permuted bf16 (convert_w_perm2). LDS swizzle byte^=((row>>1)&3)<<4 on write.
__global__ __launch_bounds__(512, 2) void gemm_qk256(
    const unsigned short* __restrict__ A, const unsigned short* __restrict__ W,
    const float* __restrict__ bias, unsigned short* __restrict__ out0,
    unsigned short* __restrict__ out1, int K) {
  __shared__ unsigned short At[2][8192];   // 256 x 32 (swizzled content)
  __shared__ unsigned short Bt[2][6144];   // 192 x 32 (swizzled content)
  const int tid = threadIdx.x;
  const int nwg = gridDim.x * gridDim.y;   // 512
  const int orig = blockIdx.y * gridDim.x + blockIdx.x;
  const int wg = (orig & 7) * (nwg >> 3) + (orig >> 3);
  const int bm = (wg % gridDim.x) * 256;
  const int bn = (wg / gridDim.x) * 192;
  const int wave = tid >> 6, lane = tid & 63;
  const int wr = wave >> 2, wc = wave & 3;          // 2(M) x 4(N)
  const int lg = lane >> 4, lr = lane & 15;

  // staging granule map: thread -> (row, col-elem); swizzled LDS byte offsets
  const int rA0 = tid >> 2,           cA0 = (tid & 3) << 3;
  const int rA1 = (tid + 512) >> 2;                          // rows 128..255
  const bool hasB1 = tid < 256;
  const int rB1 = (tid + 512) >> 2;                          // rows 128..191 (tid<256)
  const int dA0 = rA0 * 64 + ((cA0 << 1) ^ (((rA0 >> 1) & 3) << 4));
  const int dA1 = rA1 * 64 + ((cA0 << 1) ^ (((rA1 >> 1) & 3) << 4));
  const int dB0 = dA0;
  const int dB1 = rB1 * 64 + ((cA0 << 1) ^ (((rB1 >> 1) & 3) << 4));
  const unsigned short* pA0 = A + (size_t)(bm + rA0) * K + cA0;
  const unsigned short* pA1 = A + (size_t)(bm + rA1) * K + cA0;
  const unsigned short* pB0 = W + (size_t)(bn + rA0) * K + cA0;
  const unsigned short* pB1 = W + (size_t)(bn + rB1) * K + cA0;

  // two NAMED register staging sets (rule #20: no runtime-indexed reg arrays)
  u16x8 a0A = {}, a1A = {}, b0A = {}, b1A = {};
  u16x8 a0B = {}, a1B = {}, b0B = {}, b1B = {};

  auto gloadA = [&](int k0) {
    a0A = *reinterpret_cast<const u16x8*>(pA0 + k0);
    a1A = *reinterpret_cast<const u16x8*>(pA1 + k0);
    b0A = *reinterpret_cast<const u16x8*>(pB0 + k0);
    if (hasB1) b1A = *reinterpret_cast<const u16x8*>(pB1 + k0);
  };
  auto gloadB = [&](int k0) {
    a0B = *reinterpret_cast<const u16x8*>(pA0 + k0);
    a1B = *reinterpret_cast<const u16x8*>(pA1 + k0);
    b0B = *reinterpret_cast<const u16x8*>(pB0 + k0);
    if (hasB1) b1B = *reinterpret_cast<const u16x8*>(pB1 + k0);
  };
  auto lwriteA = [&](int buf) {
    *reinterpret_cast<u16x8*>((char*)At[buf] + dA0) = a0A;
    *reinterpret_cast<u16x8*>((char*)At[buf] + dA1) = a1A;
    *reinterpret_cast<u16x8*>((char*)Bt[buf] + dB0) = b0A;
    if (hasB1) *reinterpret_cast<u16x8*>((char*)Bt[buf] + dB1) = b1A;
  };
  auto lwriteB = [&](int buf) {
    *reinterpret_cast<u16x8*>((char*)At[buf] + dA0) = a0B;
    *reinterpret_cast<u16x8*>((char*)At[buf] + dA1) = a1B;
    *reinterpret_cast<u16x8*>((char*)Bt[buf] + dB0) = b0B;
    if (hasB1) *reinterpret_cast<u16x8*>((char*)Bt[buf] + dB1) = b1B;
  };

  // read-side swizzle depends only on lr (row bases are multiples of 16)
  const int rdswz = ((((lr >> 1) & 3) ^ lg) << 4);   // byte offset within 64B row

  f32x4 acc[8][3] = {};
  auto compute = [&](int buf) {
    bf16x8 af[8], bfr[3];
    const char* abase = (const char*)At[buf];
    const char* bbase = (const char*)Bt[buf];
#pragma unroll
    for (int mi = 0; mi < 8; ++mi) {
      const int row = wr * 128 + mi * 16 + lr;
      af[mi] = *reinterpret_cast<const bf16x8*>(abase + row * 64 + rdswz);
    }
#pragma unroll
    for (int ni = 0; ni < 3; ++ni) {
      const int row = wc * 48 + ni * 16 + lr;
      bfr[ni] = *reinterpret_cast<const bf16x8*>(bbase + row * 64 + rdswz);
    }
#pragma unroll
    for (int mi = 0; mi < 8; ++mi)
#pragma unroll
      for (int ni = 0; ni < 3; ++ni)
        acc[mi][ni] = __builtin_amdgcn_mfma_f32_16x16x32_bf16(af[mi], bfr[ni], acc[mi][ni], 0, 0, 0);
  };

  const int NT = K / 32;                 // 24 (even)
  // prologue: tile0 -> setA -> LDS0; tile1 -> setB (stays in regs until phase 0)
  gloadA(0);
  gloadB(32);
  lwriteA(0);
  __syncthreads();

  for (int tt = 0; tt < NT; tt += 2) {
    // even phase: tile tt from LDS0
    if (tt + 2 < NT) gloadA((tt + 2) * 32);     // in flight for ~2 phases
    compute(0);
    if (tt + 1 < NT) lwriteB(1);                // waits on loads issued last odd phase
    __syncthreads();
    // odd phase: tile tt+1 from LDS1
    if (tt + 1 < NT) {
      if (tt + 3 < NT) gloadB((tt + 3) * 32);
      compute(1);
      if (tt + 2 < NT) lwriteA(0);              // waits on loads issued last even phase
      __syncthreads();
    }
  }

  unsigned short* outp = out0;
  int nbase = 0;
  float scale = 0.125f;                 // Qd pre-scaled by 1/8
  if (bn >= NQD) { outp = out1; nbase = NQD; scale = 1.0f; }
#pragma unroll
  for (int mi = 0; mi < 8; ++mi)
#pragma unroll
    for (int ni = 0; ni < 3; ++ni)
#pragma unroll
      for (int i = 0; i < 4; ++i) {
        int m = bm + wr * 128 + mi * 16 + lg * 4 + i;
        int n = bn + wc * 48 + ni * 16 + lr;
        float v = (acc[mi][ni][i] + bias[n]) * scale;
        int nr = n - nbase;
        size_t addr = ((size_t)(((m >> 9) * 12 + (nr >> 9)) * 8 + ((nr >> 6) & 7)) * 512 + (size_t)(m & 511)) * 64 + (size_t)(nr & 63);
        outp[addr] = f2bf(v);
      }
}

// ---------------------------------------------------------------- fused attention, 32x32 swapped structure (+ T5 setprio)
__global__ __launch_bounds__(256) void attn32(
    const unsigned short* __restrict__ Qd, const unsigned short* __restrict__ Kd,
    const unsigned short* __restrict__ Vt, const int* __restrict__ mask,
    float* __restrict__ out) {
  __shared__ unsigned char KsB[64 * 128];   // [k][e] bf16, byte^((row&7)<<4) swizzle
  __shared__ unsigned char VsB[64 * 128];   // [e][k] bf16, same swizzle
  __shared__ float mLds[64];
  __shared__ int mflag;
  const int tid = threadIdx.x;
  const int bid = blockIdx.x;
  const int qt = bid & 3;
  const int inst = bid >> 2;         // (b*12+h)*8 + d
  const int bh = inst >> 3;
  const int b = bh / 12;
  const int wave = tid >> 6, lane = tid & 63;
  const int l31 = lane & 31, hi = lane >> 5;
  const size_t qkbase = (size_t)inst * (SS * 64);
  const size_t vbase = (size_t)bh * (64 * SS);

  if (tid == 0) mflag = 0;
  __syncthreads();
  {
    int m0 = mask[b * SS + tid], m1 = mask[b * SS + 256 + tid];
    if ((m0 == 0) || (m1 == 0)) mflag = 1;
  }
  __syncthreads();
  const bool hasmask = (mflag != 0);

  const int q0w = qt * 128 + wave * 32;
  bf16x8 aq[4];
  {
    const unsigned short* qrow = Qd + qkbase + (size_t)(q0w + l31) * 64 + 8 * hi;
#pragma unroll
    for (int s = 0; s < 4; ++s)
      aq[s] = *reinterpret_cast<const bf16x8*>(qrow + 16 * s);
  }

  const int sr = tid >> 3;
  const int sc = (tid & 7) * 8;
  const int swz_lo = sr * 128 + ((sc * 2) ^ ((sr & 7) << 4));
  const int swz_hi = (sr + 32) * 128 + ((sc * 2) ^ (((sr + 32) & 7) << 4));

  f32x16 o[2] = {};
  float psum = 0.f;

  u16x8 rk0 = *reinterpret_cast<const u16x8*>(&Kd[qkbase + (size_t)sr * 64 + sc]);
  u16x8 rk1 = *reinterpret_cast<const u16x8*>(&Kd[qkbase + (size_t)(sr + 32) * 64 + sc]);
  u16x8 rv0 = *reinterpret_cast<const u16x8*>(&Vt[vbase + (size_t)sr * SS + sc]);
  u16x8 rv1 = *reinterpret_cast<const u16x8*>(&Vt[vbase + (size_t)(sr + 32) * SS + sc]);

  for (int t = 0; t < SS / 64; ++t) {
    *reinterpret_cast<u16x8*>(KsB + swz_lo) = rk0;
    *reinterpret_cast<u16x8*>(KsB + swz_hi) = rk1;
    *reinterpret_cast<u16x8*>(VsB + swz_lo) = rv0;
    *reinterpret_cast<u16x8*>(VsB + swz_hi) = rv1;
    if (hasmask && tid < 64) mLds[tid] = mask[b * SS + t * 64 + tid] ? 0.f : -1e9f;
    __syncthreads();

    if (t < SS / 64 - 1) {
      const int kn = (t + 1) * 64;
      rk0 = *reinterpret_cast<const u16x8*>(&Kd[qkbase + (size_t)(kn + sr) * 64 + sc]);
      rk1 = *reinterpret_cast<const u16x8*>(&Kd[qkbase + (size_t)(kn + sr + 32) * 64 + sc]);
      rv0 = *reinterpret_cast<const u16x8*>(&Vt[vbase + (size_t)sr * SS + kn + sc]);
      rv1 = *reinterpret_cast<const u16x8*>(&Vt[vbase + (size_t)(sr + 32) * SS + kn + sc]);
    }

    f32x16 st[2];
    __builtin_amdgcn_s_setprio(1);
#pragma unroll
    for (int kh = 0; kh < 2; ++kh) {
      f32x16 acc = {};
      const int row = kh * 32 + l31;
      const int rswz = (row & 7) << 4;
#pragma unroll
      for (int s = 0; s < 4; ++s) {
        bf16x8 ak = *reinterpret_cast<const bf16x8*>(KsB + row * 128 + ((32 * s + 16 * hi) ^ rswz));
        acc = __builtin_amdgcn_mfma_f32_32x32x16_bf16(ak, aq[s], acc, 0, 0, 0);
      }
      st[kh] = acc;
    }
    __builtin_amdgcn_s_setprio(0);

    if (hasmask) {
#pragma unroll
      for (int h = 0; h < 2; ++h)
#pragma unroll
        for (int r = 0; r < 16; ++r)
          st[h][r] += mLds[32 * h + (r & 3) + 8 * (r >> 2) + 4 * hi];
    }

    float pv[2][16];
#pragma unroll
    for (int h = 0; h < 2; ++h)
#pragma unroll
      for (int r = 0; r < 16; ++r) {
        float p = __expf(st[h][r]);
        psum += p;
        pv[h][r] = p;
      }

    __builtin_amdgcn_s_setprio(1);
#pragma unroll
    for (int ks = 0; ks < 4; ++ks) {
      const int h = ks >> 1, rb = 8 * (ks & 1);
      unsigned w0 = cvt_pk_bf16(pv[h][rb + 0], pv[h][rb + 1]);
      unsigned w1 = cvt_pk_bf16(pv[h][rb + 2], pv[h][rb + 3]);
      unsigned w2 = cvt_pk_bf16(pv[h][rb + 4], pv[h][rb + 5]);
      unsigned w3 = cvt_pk_bf16(pv[h][rb + 6], pv[h][rb + 7]);
      asm("v_permlane32_swap_b32 %0, %1" : "+v"(w0), "+v"(w2));
      asm("v_permlane32_swap_b32 %0, %1" : "+v"(w1), "+v"(w3));
      union { unsigned u[4]; bf16x8 v; } pa;
      pa.u[0] = w0; pa.u[1] = w1; pa.u[2] = w2; pa.u[3] = w3;
#pragma unroll
      for (int et = 0; et < 2; ++et) {
        const int vrow = 32 * et + l31;
        bf16x8 bv = *reinterpret_cast<const bf16x8*>(
            VsB + vrow * 128 + ((32 * ks + 16 * hi) ^ ((vrow & 7) << 4)));
        o[et] = __builtin_amdgcn_mfma_f32_32x32x16_bf16(pa.v, bv, o[et], 0, 0, 0);
      }
    }
    __builtin_amdgcn_s_setprio(0);
    __syncthreads();
  }

  psum += __shfl_xor(psum, 32);
  float inv = 1.f / psum;
  float iv[16];
#pragma unroll
  for (int r = 0; r < 16; ++r)
    iv[r] = __shfl(inv, (r & 3) + 8 * (r >> 2) + 4 * hi);

  const int d = inst & 7;
  const int hh = bh % 12;
  const size_t obase = (((size_t)d * BB + b) * HEADS + hh) * (SS * 64);
#pragma unroll
  for (int et = 0; et < 2; ++et)
#pragma unroll
    for (int r = 0; r < 16; ++r) {
      const int qrow = (r & 3) + 8 * (r >> 2) + 4 * hi;
      out[obase + (size_t)(q0w + qrow) * 64 + 32 * et + l31] = o[et][r] * iv[r];
    }
}

// ----------------------------------------------------------------
extern "C" void kernel_launch(void* const* d_in, const int* in_sizes, int n_in,
                              void* d_out, int out_size, void* d_ws, size_t ws_size,
                              hipStream_t stream) {
  const float* hs  = (const float*)d_in[0];
  const int* mask  = (const int*)d_in[1];
  const float* Wv  = (const float*)d_in[6];
  const float* bv  = (const float*)d_in[7];
  const float* Wqd = (const float*)d_in[8];
  const float* bqd = (const float*)d_in[9];
  const float* Wkd = (const float*)d_in[10];
  const float* bkd = (const float*)d_in[11];

  char* ws = (char*)d_ws;
  unsigned short* A_bf   = (unsigned short*)ws; ws += (size_t)MM * HIDDEN * 2;
  unsigned short* Wv_bf  = (unsigned short*)ws; ws += (size_t)HIDDEN * HIDDEN * 2;
  unsigned short* Wqk_bf = (unsigned short*)ws; ws += (size_t)(2 * NQD) * HIDDEN * 2; // Wqd|Wkd permuted
  float*          bqk_p  = (float*)ws;          ws += (size_t)(2 * NQD) * 4;          // permuted biases
  unsigned short* Qd     = (unsigned short*)ws; ws += (size_t)MM * NQD * 2;
  unsigned short* Kd     = (unsigned short*)ws; ws += (size_t)MM * NQD * 2;
  unsigned short* Vt     = (unsigned short*)ws; ws += (size_t)MM * HIDDEN * 2;

  {
    int a4 = MM * HIDDEN / 4, b4 = HIDDEN * HIDDEN / 4;
    convert2_f32_bf16<<<(a4 + b4 + 255) / 256, 256, 0, stream>>>(hs, A_bf, a4, Wv, Wv_bf, b4);
  }
  {
    int n4 = NQD * HIDDEN / 4;
    convert_w_perm2<<<(2 * n4 + 255) / 256, 256, 0, stream>>>(Wqd, Wkd, Wqk_bf, n4);
    convert_bias_perm2<<<(2 * NQD + 255) / 256, 256, 0, stream>>>(bqd, bkd, bqk_p, NQD);
  }

  // V^T gemm: A=Wv (M=768), W=X (N=2048) -> Vt[bh][e][s]
  gemm_bt<<<dim3(HIDDEN / 128, MM / 128), 256, 0, stream>>>(
      Wv_bf, A_bf, bv, Vt, HIDDEN);
  // merged Qd|Kd gemm: A=X (M=2048), W=Wqk (N=12288), 256x192 tile, 512 blocks
  gemm_qk256<<<dim3(MM / 256, 2 * NQD / 192), 512, 0, stream>>>(
      A_bf, Wqk_bf, bqk_p, Qd, Kd, HIDDEN);

  attn32<<<BB * HEADS * DEPTH * (SS / 128), 256, 0, stream>>>(Qd, Kd, Vt, mask, (float*)d_out);
}